// Round 16
// baseline (548.745 us; speedup 1.0000x reference)
//
#include <hip/hip_runtime.h>
#include <hip/hip_cooperative_groups.h>
#include <stdint.h>

#define NN 50000
#define NE 1600000
#define BSH 7              // bucket = 128 dst nodes
#define NBK 391            // ceil(NN/128) buckets == grid blocks
#define CAP 4608           // ebuf slots per bucket (mean 4092, +8 sigma)
#define ECH2 4093          // edges per block (391*4093 >= NE, last short)
#define TPB 256

namespace cg = cooperative_groups;

__global__ __launch_bounds__(TPB, 2) void k_mega(
    const int* __restrict__ esrc, const int* __restrict__ edst,
    const float* __restrict__ W1, const float* __restrict__ b1,
    const float* __restrict__ W2, const float* __restrict__ b2,
    const float* __restrict__ Wc, const float* __restrict__ bc,
    const float* __restrict__ X, float* __restrict__ out,
    int* __restrict__ bh, int* __restrict__ boff, int* __restrict__ btot,
    uint32_t* __restrict__ ebuf, float* __restrict__ dinv,
    float* __restrict__ Wcb, float* __restrict__ c12, float* __restrict__ Yraw,
    float* __restrict__ U, float* __restrict__ V)
{
  cg::grid_group grid = cg::this_grid();
  __shared__ __align__(16) char smem[29216];
  const int t = threadIdx.x;
  const int b = blockIdx.x;

  // ================= P0: per-block bucket histogram + wcombo (blocks 0..8) =================
  {
    int* h = (int*)smem;                   // [0, 3128): 2-way split counters
    float* M1 = (float*)(smem + 3200);     // [3200, 7296)
    for (int i = t; i < 2 * NBK; i += TPB) h[i] = 0;
    __syncthreads();
    if (b < 9){
      for (int idx = t; idx < 1024; idx += TPB){
        int k = idx >> 3, c = idx & 7;
        float s = 0.f;
        for (int j = 0; j < 64; ++j) s += W2[k * 64 + j] * Wc[j * 8 + c];
        M1[idx] = s;
      }
      __syncthreads();
      if (b < 8){
        int i = b * 32 + (t >> 3), c = t & 7;
        float s = 0.f;
        for (int k = 0; k < 128; ++k) s += W1[i * 128 + k] * M1[k * 8 + c];
        Wcb[i * 8 + c] = s;
      } else {
        if (t < 8){
          float s = 0.f;
          for (int k = 0; k < 128; ++k) s += b1[k] * M1[k * 8 + t];
          c12[t] = s;
        } else if (t < 16){
          int c = t - 8;
          float s = bc[c];
          for (int k = 0; k < 64; ++k) s += b2[k] * Wc[k * 8 + c];
          c12[t] = s;
        }
      }
    }
    const int g = (t & 1) * NBK;
    const int e0 = b * ECH2;
    const int e1 = (e0 + ECH2 < NE) ? e0 + ECH2 : NE;
    for (int e = e0 + t; e < e1; e += TPB)
      atomicAdd(&h[g + (edst[e] >> BSH)], 1);
    __syncthreads();
    for (int i = t; i < NBK; i += TPB)
      bh[(size_t)b * NBK + i] = h[i] + h[NBK + i];
  }
  __threadfence();
  grid.sync();

  // ================= P1: block b scans column bh[*][b] =================
  {
    int* lds = (int*)smem;                 // 512 ints
    const int i0 = t, i1 = t + 256;
    int v0 = (i0 < NBK) ? bh[(size_t)i0 * NBK + b] : 0;
    int v1 = (i1 < NBK) ? bh[(size_t)i1 * NBK + b] : 0;
    lds[i0] = v0; lds[i1] = v1;
    __syncthreads();
    for (int ofs = 1; ofs < 512; ofs <<= 1){
      int a0 = (i0 >= ofs) ? lds[i0 - ofs] : 0;
      int a1 = (i1 >= ofs) ? lds[i1 - ofs] : 0;
      __syncthreads();
      lds[i0] += a0; lds[i1] += a1;
      __syncthreads();
    }
    if (i0 < NBK) boff[(size_t)i0 * NBK + b] = lds[i0] - v0;
    if (i1 < NBK) boff[(size_t)i1 * NBK + b] = lds[i1] - v1;
    if (t == 0) btot[b] = lds[NBK - 1];
  }
  __threadfence();
  grid.sync();

  // ================= P2: LDS-staged two-phase scatter =================
  {
    uint32_t* lbuf = (uint32_t*)smem;            // [0, 16372)
    int* lcnt  = (int*)(smem + 16372);           // [16372, 17936)
    int* lst   = (int*)(smem + 17936);           // [17936, 19984): 512-slot scan
    int* dbase = (int*)(smem + 19984);           // [19984, 21548)
    for (int i = t; i < NBK; i += TPB){
      lcnt[i] = 0;
      dbase[i] = i * CAP + boff[(size_t)b * NBK + i];
    }
    const int i0 = t, i1 = t + 256;
    int m0 = (i0 < NBK) ? bh[(size_t)b * NBK + i0] : 0;
    int m1 = (i1 < NBK) ? bh[(size_t)b * NBK + i1] : 0;
    lst[i0] = m0; lst[i1] = m1;
    __syncthreads();
    for (int ofs = 1; ofs < 512; ofs <<= 1){
      int a0 = (i0 >= ofs) ? lst[i0 - ofs] : 0;
      int a1 = (i1 >= ofs) ? lst[i1 - ofs] : 0;
      __syncthreads();
      lst[i0] += a0; lst[i1] += a1;
      __syncthreads();
    }
    int ex0 = lst[i0] - m0, ex1 = lst[i1] - m1;
    __syncthreads();
    lst[i0] = ex0; lst[i1] = ex1;
    __syncthreads();
    const int e0 = b * ECH2;
    const int e1 = (e0 + ECH2 < NE) ? e0 + ECH2 : NE;
    for (int e = e0 + t; e < e1; e += TPB){
      int d = edst[e];
      int s = esrc[e];
      int bk = d >> BSH;
      int p = atomicAdd(&lcnt[bk], 1);
      lbuf[lst[bk] + p] = ((uint32_t)s << 16) | (uint32_t)d;
    }
    __syncthreads();
    const int tot = e1 - e0;
    for (int k = t; k < tot; k += TPB){
      uint32_t v = lbuf[k];
      int bk = (int)(v & 0xFFFFu) >> BSH;
      ebuf[dbase[bk] + (k - lst[bk])] = v;
    }
  }
  __threadfence();
  grid.sync();

  // ================= P3: per-bucket degree/dinv + Yraw = X @ Wcb =================
  {
    int* h = (int*)smem;                   // [0, 512)
    float* Wl = (float*)(smem + 1024);     // [1024, 9216)
    if (t < 128) h[t] = 0;
    for (int i = t; i < 2048; i += TPB) Wl[i] = Wcb[i];
    __syncthreads();
    const int base = b * CAP;
    const int cnt = btot[b];
    for (int e = base + t; e < base + cnt; e += TPB)
      atomicAdd(&h[ebuf[e] & 127], 1);
    __syncthreads();
    int node = (b << BSH) + t;
    if (t < 128 && node < NN)
      dinv[node] = rsqrtf((float)(h[t] + 1));
    // y: this bucket's 128 rows, 4 rows per thread, 8 lanes per row
    const int rl = t >> 3, c = t & 7;
    const float* Xp0; const float* Xp1; const float* Xp2; const float* Xp3;
    int r0 = b * 128 + rl,      rc0 = r0 < NN ? r0 : NN - 1;
    int r1 = r0 + 32,           rc1 = r1 < NN ? r1 : NN - 1;
    int r2 = r0 + 64,           rc2 = r2 < NN ? r2 : NN - 1;
    int r3 = r0 + 96,           rc3 = r3 < NN ? r3 : NN - 1;
    Xp0 = X + (size_t)rc0 * 256; Xp1 = X + (size_t)rc1 * 256;
    Xp2 = X + (size_t)rc2 * 256; Xp3 = X + (size_t)rc3 * 256;
    float a0 = 0.f, a1 = 0.f, a2 = 0.f, a3 = 0.f;
    #pragma unroll 4
    for (int k = 0; k < 256; k += 4){
      float w0 = Wl[k * 8 + c],      w1 = Wl[(k + 1) * 8 + c];
      float w2 = Wl[(k + 2) * 8 + c], w3 = Wl[(k + 3) * 8 + c];
      float4 x0 = *(const float4*)(Xp0 + k);
      float4 x1 = *(const float4*)(Xp1 + k);
      float4 x2 = *(const float4*)(Xp2 + k);
      float4 x3 = *(const float4*)(Xp3 + k);
      a0 += x0.x * w0 + x0.y * w1 + x0.z * w2 + x0.w * w3;
      a1 += x1.x * w0 + x1.y * w1 + x1.z * w2 + x1.w * w3;
      a2 += x2.x * w0 + x2.y * w1 + x2.z * w2 + x2.w * w3;
      a3 += x3.x * w0 + x3.y * w1 + x3.z * w2 + x3.w * w3;
    }
    if (r0 < NN) Yraw[(size_t)r0 * 8 + c] = a0;
    if (r1 < NN) Yraw[(size_t)r1 * 8 + c] = a1;
    if (r2 < NN) Yraw[(size_t)r2 * 8 + c] = a2;
    if (r3 < NN) Yraw[(size_t)r3 * 8 + c] = a3;
  }
  __threadfence();
  grid.sync();

  // ================= P4: bin bucket edges in LDS + fused agg1 =================
  unsigned short* lcsr = (unsigned short*)(smem + 18432);  // persists into P5
  int* hst = (int*)(smem + 28672);                         // persists into P5
  int* sbp = (int*)(smem + 28160);                         // persists into P5
  {
    uint32_t* lede = (uint32_t*)smem;          // [0, 18432)
    int* h = (int*)(smem + 27648);             // [27648, 28160)
    const int base = b * CAP;
    const int cnt = btot[b];
    for (int i = t; i < cnt; i += TPB) lede[i] = ebuf[base + i];
    if (t < 128) h[t] = 0;
    __syncthreads();
    for (int i = t; i < cnt; i += TPB)
      atomicAdd(&h[lede[i] & 127], 1);
    __syncthreads();
    int deg = (t < 128) ? h[t] : 0;
    for (int ofs = 1; ofs < 128; ofs <<= 1){
      int tv = (t >= ofs && t < 128) ? h[t - ofs] : 0;
      __syncthreads();
      if (t < 128) h[t] += tv;
      __syncthreads();
    }
    int excl = (t < 128) ? (h[t] - deg) : 0;
    __syncthreads();
    if (t < 128){ sbp[t] = excl; hst[t] = excl; }
    __syncthreads();
    for (int i = t; i < cnt; i += TPB){
      uint32_t v = lede[i];
      int p = atomicAdd(&sbp[v & 127], 1);
      lcsr[p] = (unsigned short)(v >> 16);
    }
    __syncthreads();
    // fused agg1 from LDS: U = di^2*(sum dinv_s*Y_s + di*Y_d); V = di*(sum dinv_s + di)
    const int rl = t >> 3, c = t & 7;
    #pragma unroll
    for (int j = 0; j < 4; ++j){
      int ln = rl + 32 * j;
      int nd = (b << BSH) + ln;
      if (nd < NN){
        int e = hst[ln];
        const int e1 = sbp[ln];
        float a = 0.f, vd = 0.f;
        for (; e + 4 <= e1; e += 4){
          int s0 = lcsr[e], s1 = lcsr[e + 1], s2 = lcsr[e + 2], s3 = lcsr[e + 3];
          float d0 = dinv[s0], d1 = dinv[s1], d2 = dinv[s2], d3 = dinv[s3];
          float y0 = Yraw[(size_t)s0 * 8 + c], y1 = Yraw[(size_t)s1 * 8 + c];
          float y2 = Yraw[(size_t)s2 * 8 + c], y3 = Yraw[(size_t)s3 * 8 + c];
          a += (d0 * y0 + d1 * y1) + (d2 * y2 + d3 * y3);
          vd += (d0 + d1) + (d2 + d3);
        }
        for (; e < e1; ++e){
          int s0 = lcsr[e];
          float d0 = dinv[s0];
          a += d0 * Yraw[(size_t)s0 * 8 + c];
          vd += d0;
        }
        float di = dinv[nd];
        U[(size_t)nd * 8 + c] = di * di * (a + di * Yraw[(size_t)nd * 8 + c]);
        if (c == 0) V[nd] = di * (vd + di);
      }
    }
  }
  __threadfence();
  grid.sync();

  // ================= P5: agg2 from still-resident LDS edge lists =================
  {
    const int rl = t >> 3, c = t & 7;
    const float c1 = c12[c], c2v = c12[8 + c];
    #pragma unroll
    for (int j = 0; j < 4; ++j){
      int ln = rl + 32 * j;
      int nd = (b << BSH) + ln;
      if (nd < NN){
        int e = hst[ln];
        const int e1 = sbp[ln];
        float a = 0.f;
        for (; e + 4 <= e1; e += 4){
          int s0 = lcsr[e], s1 = lcsr[e + 1], s2 = lcsr[e + 2], s3 = lcsr[e + 3];
          float y0 = U[(size_t)s0 * 8 + c], y1 = U[(size_t)s1 * 8 + c];
          float y2 = U[(size_t)s2 * 8 + c], y3 = U[(size_t)s3 * 8 + c];
          a += (y0 + y1) + (y2 + y3);
        }
        for (; e < e1; ++e)
          a += U[(size_t)lcsr[e] * 8 + c];
        float di = dinv[nd];
        out[(size_t)nd * 8 + c] = di * (a + U[(size_t)nd * 8 + c]) + V[nd] * c1 + c2v;
      }
    }
  }
}

extern "C" void kernel_launch(void* const* d_in, const int* in_sizes, int n_in,
                              void* d_out, int out_size, void* d_ws, size_t ws_size,
                              hipStream_t stream) {
  const int*   ei  = (const int*)d_in[1];
  const int*   esrc = ei;
  const int*   edst = ei + NE;
  const float* seq = (const float*)d_in[0];
  const float* W1 = (const float*)d_in[2];
  const float* b1 = (const float*)d_in[3];
  const float* W2 = (const float*)d_in[4];
  const float* b2 = (const float*)d_in[5];
  const float* Wc = (const float*)d_in[6];
  const float* bc = (const float*)d_in[7];
  float* out = (float*)d_out;

  char* ws = (char*)d_ws;
  size_t o = 0;
  auto alloc = [&](size_t bytes) -> void* {
    void* p = ws + o;
    o += (bytes + 255) & ~(size_t)255;
    return p;
  };
  int*      bh    = (int*)alloc((size_t)NBK * NBK * 4);
  int*      boff  = (int*)alloc((size_t)NBK * NBK * 4);
  int*      btot  = (int*)alloc((size_t)NBK * 4);
  uint32_t* ebuf  = (uint32_t*)alloc((size_t)NBK * CAP * 4);
  float*    dinv  = (float*)alloc((size_t)NN * 4);
  float*    Wcb   = (float*)alloc(2048 * 4);
  float*    c12   = (float*)alloc(16 * 4);
  float*    Yraw  = (float*)alloc((size_t)NN * 8 * 4);
  float*    U     = (float*)alloc((size_t)NN * 8 * 4);
  float*    V     = (float*)alloc((size_t)NN * 4);

  void* args[] = {
    (void*)&esrc, (void*)&edst, (void*)&W1, (void*)&b1, (void*)&W2, (void*)&b2,
    (void*)&Wc, (void*)&bc, (void*)&seq, (void*)&out,
    (void*)&bh, (void*)&boff, (void*)&btot, (void*)&ebuf, (void*)&dinv,
    (void*)&Wcb, (void*)&c12, (void*)&Yraw, (void*)&U, (void*)&V
  };
  hipLaunchCooperativeKernel(reinterpret_cast<void*>(k_mega),
                             dim3(NBK), dim3(TPB), args, 0, stream);
}

// Round 17
// 87.850 us; speedup vs baseline: 6.2464x; 6.2464x over previous
//
#include <hip/hip_runtime.h>
#include <hip/hip_bf16.h>
#include <stdint.h>

#define NN 50000
#define NE 1600000
#define BSH 7            // bucket = 128 dst nodes
#define NBK 391          // ceil(NN/128)
#define CAP 4608         // slots per bucket (mean 4096, sigma~64, +8 sigma)
#define NSB 256          // edge-pass blocks
#define ECH 6250         // edges per block (NSB*ECH == NE exactly)
#define EPAIR 3125       // int2 pairs per block

// ---------------- launch 1: [wcombo: block 0 | hist: blocks 1..256] ----------------
__global__ __launch_bounds__(1024) void k_iw(const float* __restrict__ W1, const float* __restrict__ b1,
                                             const float* __restrict__ W2, const float* __restrict__ b2,
                                             const float* __restrict__ Wc, const float* __restrict__ bc,
                                             float* __restrict__ Wcombo, float* __restrict__ c12,
                                             const int* __restrict__ dst, int* __restrict__ bh){
  const int t = threadIdx.x;
  if (blockIdx.x == 0){
    __shared__ float M1[1024];
    { // M1 = W2@Wc [128,8], one element per thread
      int k = t >> 3, c = t & 7;
      float s = 0.f;
      for (int j = 0; j < 64; ++j) s += W2[k * 64 + j] * Wc[j * 8 + c];
      M1[t] = s;
    }
    __syncthreads();
    for (int idx = t; idx < 2048; idx += 1024){
      int i = idx >> 3, c = idx & 7;
      float s = 0.f;
      for (int k = 0; k < 128; ++k) s += W1[i * 128 + k] * M1[k * 8 + c];
      Wcombo[idx] = s;
    }
    if (t < 8){
      float s = 0.f;
      for (int k = 0; k < 128; ++k) s += b1[k] * M1[k * 8 + t];
      c12[t] = s;
    } else if (t < 16){
      int c = t - 8;
      float s = bc[c];
      for (int k = 0; k < 64; ++k) s += b2[k] * Wc[k * 8 + c];
      c12[t] = s;
    }
  } else {
    __shared__ int h[4 * NBK];
    const int hb = blockIdx.x - 1;
    for (int i = t; i < 4 * NBK; i += 1024) h[i] = 0;
    __syncthreads();
    const int g = (t >> 8) * NBK;      // 4-way split histogram
    const int2* dp = (const int2*)(dst + hb * ECH);
    for (int i = t; i < EPAIR; i += 1024){
      int2 d = dp[i];
      atomicAdd(&h[g + (d.x >> BSH)], 1);
      atomicAdd(&h[g + (d.y >> BSH)], 1);
    }
    __syncthreads();
    for (int i = t; i < NBK; i += 1024)
      bh[(size_t)hb * NBK + i] = h[i] + h[NBK + i] + h[2 * NBK + i] + h[3 * NBK + i];
  }
}

// ---------------- launch 2: per-bucket exclusive scan over the NSB blocks ----------------
__global__ __launch_bounds__(NSB) void k_bscan(const int* __restrict__ bh, int* __restrict__ boff,
                                               int* __restrict__ btot){
  __shared__ int lds[NSB];
  const int b = blockIdx.x;
  int v = bh[(size_t)threadIdx.x * NBK + b];
  lds[threadIdx.x] = v;
  __syncthreads();
  for (int ofs = 1; ofs < NSB; ofs <<= 1){
    int t = (threadIdx.x >= ofs) ? lds[threadIdx.x - ofs] : 0;
    __syncthreads();
    lds[threadIdx.x] += t;
    __syncthreads();
  }
  boff[(size_t)threadIdx.x * NBK + b] = lds[threadIdx.x] - v;
  if (threadIdx.x == NSB - 1) btot[b] = lds[NSB - 1];
}

// ---------------- launch 3: [scat (LDS-staged): blocks 0..255 | Yraw: blocks 256..646] ----------------
__global__ __launch_bounds__(1024) void k_sy(const int* __restrict__ src, const int* __restrict__ dst,
                                             const int* __restrict__ bh, const int* __restrict__ boff,
                                             uint32_t* __restrict__ ebuf,
                                             const float* __restrict__ X, const float* __restrict__ Wcombo,
                                             float* __restrict__ Yraw){
  const int t = threadIdx.x;
  if (blockIdx.x < NSB){
    __shared__ uint32_t lbuf[ECH];     // 25 KB: block's edges grouped by bucket
    __shared__ int lcnt[NBK];
    __shared__ int lst[NBK];           // exclusive local segment start per bucket
    __shared__ int dbase[NBK];         // global dest base per bucket
    const int blk = blockIdx.x;
    int myc = 0;
    if (t < NBK){
      myc = bh[(size_t)blk * NBK + t];
      lst[t] = myc;
      lcnt[t] = 0;
      dbase[t] = t * CAP + boff[(size_t)blk * NBK + t];
    }
    __syncthreads();
    // exclusive scan of lst over NBK entries (Hillis-Steele, threads t<NBK)
    for (int ofs = 1; ofs < NBK; ofs <<= 1){
      int v = (t < NBK && t >= ofs) ? lst[t - ofs] : 0;
      __syncthreads();
      if (t < NBK) lst[t] += v;
      __syncthreads();
    }
    if (t < NBK) lst[t] -= myc;        // inclusive -> exclusive
    __syncthreads();
    // phase 1: scatter edges into LDS, grouped by bucket
    const int2* dp = (const int2*)(dst + blk * ECH);
    const int2* sp = (const int2*)(src + blk * ECH);
    for (int i = t; i < EPAIR; i += 1024){
      int2 d = dp[i];
      int2 s = sp[i];
      int b0 = d.x >> BSH;
      int p0 = atomicAdd(&lcnt[b0], 1);
      lbuf[lst[b0] + p0] = ((uint32_t)s.x << 16) | (uint32_t)d.x;
      int b1i = d.y >> BSH;
      int p1 = atomicAdd(&lcnt[b1i], 1);
      lbuf[lst[b1i] + p1] = ((uint32_t)s.y << 16) | (uint32_t)d.y;
    }
    __syncthreads();
    // phase 2: segment-local coalesced copy-out (runs of ~16 consecutive dest addresses)
    for (int k = t; k < ECH; k += 1024){
      uint32_t v = lbuf[k];
      int b = (int)(v & 0xFFFFu) >> BSH;
      ebuf[dbase[b] + (k - lst[b])] = v;
    }
  } else {
    __shared__ float Wl[2048];
    for (int i = t; i < 2048; i += 1024) Wl[i] = Wcombo[i];
    __syncthreads();
    int gid = (blockIdx.x - NSB) * 1024 + t;
    int row = gid >> 3, c = gid & 7;
    if (row >= NN) return;
    const float* Xr = X + (size_t)row * 256;
    float acc = 0.f;
    #pragma unroll 8
    for (int k = 0; k < 256; k += 4){
      float4 x = *(const float4*)(Xr + k);
      acc += x.x * Wl[k * 8 + c] + x.y * Wl[(k + 1) * 8 + c]
           + x.z * Wl[(k + 2) * 8 + c] + x.w * Wl[(k + 3) * 8 + c];
    }
    Yraw[(size_t)row * 8 + c] = acc;
  }
}

// ---------------- launch 4: per-bucket LDS-staged degree + scan + dinv + offs2 + csr ----------------
__global__ __launch_bounds__(512) void k_csr(const uint32_t* __restrict__ ebuf, const int* __restrict__ btot,
                                             float* __restrict__ dinv, int2* __restrict__ offs2,
                                             unsigned short* __restrict__ csr){
  __shared__ uint32_t lede[CAP];
  __shared__ unsigned short lcsr[CAP];
  __shared__ int h[128];
  __shared__ int sb[128];
  const int t = threadIdx.x;
  const int b = blockIdx.x;
  const int base = b * CAP;
  const int cnt = btot[b];
  for (int i = t; i < cnt; i += 512) lede[i] = ebuf[base + i];
  if (t < 128) h[t] = 0;
  __syncthreads();
  for (int i = t; i < cnt; i += 512)
    atomicAdd(&h[lede[i] & 127], 1);
  __syncthreads();
  int deg = (t < 128) ? h[t] : 0;
  for (int ofs = 1; ofs < 128; ofs <<= 1){
    int tv = (t >= ofs && t < 128) ? h[t - ofs] : 0;
    __syncthreads();
    if (t < 128) h[t] += tv;
    __syncthreads();
  }
  int excl = (t < 128) ? (h[t] - deg) : 0;
  int node = (b << BSH) + t;
  if (t < 128 && node < NN){
    dinv[node] = rsqrtf((float)(deg + 1));
    offs2[node] = make_int2(base + excl, base + excl + deg);
  }
  __syncthreads();
  if (t < 128) sb[t] = excl;
  __syncthreads();
  for (int i = t; i < cnt; i += 512){
    uint32_t v = lede[i];
    int p = atomicAdd(&sb[v & 127], 1);
    lcsr[p] = (unsigned short)(v >> 16);
  }
  __syncthreads();
  uint32_t* dstw = (uint32_t*)(csr + base);
  const uint32_t* srcw = (const uint32_t*)lcsr;
  int nw = (cnt + 1) >> 1;
  for (int i = t; i < nw; i += 512) dstw[i] = srcw[i];
}

// ---------------- launch 5: agg pass 1, 8 lanes/node ----------------
// U = di^2*(sum_s dinv_s*Yraw_s + di*Yraw_d);  V = di*(sum_s dinv_s + di)
__global__ __launch_bounds__(256) void k_agg1(const unsigned short* __restrict__ csr, const int2* __restrict__ offs2,
                                              const float* __restrict__ dinv, const float* __restrict__ Y,
                                              float* __restrict__ U, float* __restrict__ V){
  int gid = blockIdx.x * 256 + threadIdx.x;
  int node = gid >> 3, c = gid & 7;
  if (node >= NN) return;
  int2 oe = offs2[node];
  int e = oe.x;
  const int e1 = oe.y;
  float a = 0.f, vd = 0.f;
  for (; e + 4 <= e1; e += 4){
    int s0 = csr[e], s1 = csr[e + 1], s2 = csr[e + 2], s3 = csr[e + 3];
    float d0 = dinv[s0], d1 = dinv[s1], d2 = dinv[s2], d3 = dinv[s3];
    float y0 = Y[(size_t)s0 * 8 + c], y1 = Y[(size_t)s1 * 8 + c];
    float y2 = Y[(size_t)s2 * 8 + c], y3 = Y[(size_t)s3 * 8 + c];
    a += (d0 * y0 + d1 * y1) + (d2 * y2 + d3 * y3);
    vd += (d0 + d1) + (d2 + d3);
  }
  for (; e < e1; ++e){
    int s0 = csr[e];
    float d0 = dinv[s0];
    a += d0 * Y[(size_t)s0 * 8 + c];
    vd += d0;
  }
  float di = dinv[node];
  U[(size_t)node * 8 + c] = di * di * (a + di * Y[(size_t)node * 8 + c]);
  if (c == 0) V[node] = di * (vd + di);
}

// ---------------- launch 6: agg pass 2: out = di*(sum_s U_s + U_d) + V*c1 + c2 ----------------
__global__ __launch_bounds__(256) void k_agg2(const unsigned short* __restrict__ csr, const int2* __restrict__ offs2,
                                              const float* __restrict__ dinv, const float* __restrict__ U,
                                              const float* __restrict__ V, const float* __restrict__ c12,
                                              float* __restrict__ O){
  int gid = blockIdx.x * 256 + threadIdx.x;
  int node = gid >> 3, c = gid & 7;
  if (node >= NN) return;
  int2 oe = offs2[node];
  int e = oe.x;
  const int e1 = oe.y;
  float a = 0.f;
  for (; e + 4 <= e1; e += 4){
    int s0 = csr[e], s1 = csr[e + 1], s2 = csr[e + 2], s3 = csr[e + 3];
    float y0 = U[(size_t)s0 * 8 + c], y1 = U[(size_t)s1 * 8 + c];
    float y2 = U[(size_t)s2 * 8 + c], y3 = U[(size_t)s3 * 8 + c];
    a += (y0 + y1) + (y2 + y3);
  }
  for (; e < e1; ++e){
    int s0 = csr[e];
    a += U[(size_t)s0 * 8 + c];
  }
  float di = dinv[node];
  O[(size_t)node * 8 + c] = di * (a + U[(size_t)node * 8 + c]) + V[node] * c12[c] + c12[8 + c];
}

extern "C" void kernel_launch(void* const* d_in, const int* in_sizes, int n_in,
                              void* d_out, int out_size, void* d_ws, size_t ws_size,
                              hipStream_t stream) {
  const float* seq = (const float*)d_in[0];
  const int*   ei  = (const int*)d_in[1];
  const int*   esrc = ei;
  const int*   edst = ei + NE;
  const float* W1 = (const float*)d_in[2];
  const float* b1 = (const float*)d_in[3];
  const float* W2 = (const float*)d_in[4];
  const float* b2 = (const float*)d_in[5];
  const float* Wc = (const float*)d_in[6];
  const float* bc = (const float*)d_in[7];
  float* out = (float*)d_out;

  char* ws = (char*)d_ws;
  size_t o = 0;
  auto alloc = [&](size_t bytes) -> void* {
    void* p = ws + o;
    o += (bytes + 255) & ~(size_t)255;
    return p;
  };
  int*      bh    = (int*)alloc((size_t)NSB * NBK * 4);
  int*      boff  = (int*)alloc((size_t)NSB * NBK * 4);
  int*      btot  = (int*)alloc((size_t)NBK * 4);
  uint32_t* ebuf  = (uint32_t*)alloc((size_t)NBK * CAP * 4);
  unsigned short* csr = (unsigned short*)alloc((size_t)NBK * CAP * 2);
  int2*     offs2 = (int2*)alloc((size_t)NN * 8);
  float*    dinv  = (float*)alloc((size_t)NN * 4);
  float*    Wcb   = (float*)alloc(2048 * 4);
  float*    c12   = (float*)alloc(16 * 4);
  float*    Yraw  = (float*)alloc((size_t)NN * 8 * 4);
  float*    U     = (float*)alloc((size_t)NN * 8 * 4);
  float*    V     = (float*)alloc((size_t)NN * 4);

  k_iw    <<<1 + NSB, 1024, 0, stream>>>(W1, b1, W2, b2, Wc, bc, Wcb, c12, edst, bh);
  k_bscan <<<NBK, NSB, 0, stream>>>(bh, boff, btot);
  k_sy    <<<NSB + 391, 1024, 0, stream>>>(esrc, edst, bh, boff, ebuf, seq, Wcb, Yraw);
  k_csr   <<<NBK, 512, 0, stream>>>(ebuf, btot, dinv, offs2, csr);
  k_agg1  <<<1563, 256, 0, stream>>>(csr, offs2, dinv, Yraw, U, V);
  k_agg2  <<<1563, 256, 0, stream>>>(csr, offs2, dinv, U, V, c12, out);
}